// Round 7
// baseline (127.029 us; speedup 1.0000x reference)
//
#include <hip/hip_runtime.h>
#include <hip/hip_cooperative_groups.h>
#include <math.h>

#define BB 8
#define HH 256
#define WW 256
#define T  4     // rows per fused block (must divide 64) — R4-verified optimum
#define NW 4     // 256 rows / 64 bits
#define PAD 96   // envelope window padding; R>PAD handled by exact fallback
#define LDSW (WW + 2 * PAD)

typedef unsigned long long u64;

// ---------------------------------------------------------------------------
// R7: single cooperative kernel = build phase + grid.sync + R4 fused body.
// Mask layout unchanged (k innermost): masks[((b*NW + w)*WW + x)*4 + k]
//   bit ly <=> tgt[b][w*64+ly][x] == k.
// Build phase: 65536 items, each builds an 8-row u8 OCTET of one u64 word
// (oct = bits oct*8..oct*8+7, little-endian). Disjoint byte stores, no merge.
// Items live on blocks 0..255 (~1 active block per CU).
// ---------------------------------------------------------------------------
__global__ __launch_bounds__(256, 2) void mega(const int* __restrict__ tgt,
                                               const float* __restrict__ preds,
                                               u64* __restrict__ masks,
                                               float* __restrict__ out) {
  __shared__ float g[T][LDSW][4];   // squared 1-D column distances, padded rows
  __shared__ float fred[4];

  // ---------------- phase 0: build masks (distributed) --------------------
  if (blockIdx.x == 0 && threadIdx.x == 0) out[0] = 0.0f;  // before all atomics
  if (blockIdx.x < 256) {
    const int item = blockIdx.x * 256 + threadIdx.x;  // 0..65535
    const int bx = item & 255;          // column
    const int h  = (item >> 8) & 31;    // 8-row group within batch
    const int bb = item >> 13;          // batch
    const int w  = h >> 3;              // u64 word
    const int oct = h & 7;              // byte within word
    const int* p = tgt + ((size_t)bb * HH + h * 8) * WW + bx;
    unsigned c0 = 0, c1 = 0, c2 = 0, c3 = 0, bit = 1u;
    for (int r = 0; r < 8; ++r, bit += bit) {
      int e = p[r * WW];                // coalesced across bx
      c0 |= (e == 0) ? bit : 0u;
      c1 |= (e == 1) ? bit : 0u;
      c2 |= (e == 2) ? bit : 0u;
      c3 |= (e == 3) ? bit : 0u;
    }
    unsigned char* m8 = (unsigned char*)masks;
    const size_t u64idx = ((size_t)(bb * NW + w) * WW + bx) * 4;
    m8[(u64idx + 0) * 8 + oct] = (unsigned char)c0;
    m8[(u64idx + 1) * 8 + oct] = (unsigned char)c1;
    m8[(u64idx + 2) * 8 + oct] = (unsigned char)c2;
    m8[(u64idx + 3) * 8 + oct] = (unsigned char)c3;
  }

  cooperative_groups::this_grid().sync();

  // ---------------- phase 1: R4 fused body (verified absmax 0.0) ----------
  const int x  = threadIdx.x;
  const int b  = blockIdx.x >> 6;           // 64 y-tiles per batch
  const int y0 = (blockIdx.x & 63) * T;
  const int wy = y0 >> 6;           // T divides 64 -> same word for all tile rows

  // column masks for this x: 4 words x 4 classes, 32 B contiguous per thread
  u64 m[NW][4];
  {
    const u64* mb = masks + ((size_t)b * NW * WW + x) * 4;
#pragma unroll
    for (int w = 0; w < NW; ++w) {
      ulonglong2 lo = *(const ulonglong2*)(mb + (size_t)w * WW * 4 + 0);
      ulonglong2 hi = *(const ulonglong2*)(mb + (size_t)w * WW * 4 + 2);
      m[w][0] = lo.x; m[w][1] = lo.y; m[w][2] = hi.x; m[w][3] = hi.y;
    }
  }

  // prefetch epilogue preds now; latency hides under phase A + envelope
  float pr[T][4];
#pragma unroll
  for (int j = 0; j < T; ++j) {
    const float* pb = preds + ((size_t)b * 4 * HH + (y0 + j)) * WW + x;
    pr[j][0] = pb[0 * HH * WW];
    pr[j][1] = pb[1 * HH * WW];
    pr[j][2] = pb[2 * HH * WW];
    pr[j][3] = pb[3 * HH * WW];
  }

  // init padding to +INF (disjoint from the g[.][x+PAD] slots written below)
  for (int i = x; i < T * 2 * PAD; i += 256) {
    int j = i / (2 * PAD);
    int q = i - j * (2 * PAD);
    int idx = (q < PAD) ? q : (q + WW);
    *(float4*)&g[j][idx][0] = make_float4(1e30f, 1e30f, 1e30f, 1e30f);
  }

  // phase A part 1: non-own words' nearest-bit positions, shared by all rows.
  int posmax[4] = {-4096, -4096, -4096, -4096};
  int posmin[4] = { 8192,  8192,  8192,  8192};
#pragma unroll
  for (int w = 0; w < NW; ++w) {
    if (w < wy) {                    // wave-uniform branch (wy is scalar)
#pragma unroll
      for (int k = 0; k < 4; ++k) {
        u64 bits = m[w][k];
        int pos = w * 64 + 63 - __clzll((long long)bits);
        posmax[k] = max(posmax[k], bits ? pos : -4096);
      }
    } else if (w > wy) {
#pragma unroll
      for (int k = 0; k < 4; ++k) {
        u64 bits = m[w][k];
        int pos = w * 64 + (__ffsll((long long)bits) - 1);
        posmin[k] = min(posmin[k], bits ? pos : 8192);
      }
    }
  }

  // phase A part 2: per-row own-word eval + combine (exact, as verified)
  float d[T][4];                    // envelope seeds carried in registers
  int lmax = 0;
#pragma unroll
  for (int j = 0; j < T; ++j) {
    const int y  = y0 + j;
    const int ly = y & 63;
    const int ini = min(513 + y, 768 - y);   // reference INF-scan value
    float4 gv;
    float* gp_ = (float*)&gv;
#pragma unroll
    for (int k = 0; k < 4; ++k) {
      u64 bits = m[wy][k];
      u64 lo = bits & ((2ull << ly) - 1ull);  // bits 0..ly (ly=63 -> ~0)
      u64 hi = bits >> ly;                    // bit0 == bit ly
      int dl = ly - 63 + __clzll((long long)lo);
      int dh = __ffsll((long long)hi) - 1;
      int best = min(ini, y - posmax[k]);
      best = min(best, posmin[k] - y);
      best = min(best, lo ? dl : 1024);
      best = min(best, hi ? dh : 1024);
      lmax = max(lmax, best);
      float fb = (float)(best * best);
      gp_[k] = fb;
      d[j][k] = fb;                // kk = 0 seed, no LDS round-trip
    }
    *(float4*)&g[j][x + PAD][0] = gv;
  }

  // per-wave static radius bound (upper bound; per-lane exit usually earlier)
#pragma unroll
  for (int off = 32; off; off >>= 1) lmax = max(lmax, __shfl_xor(lmax, off, 64));
  const int R  = __builtin_amdgcn_readfirstlane(lmax);
  const int Rw = min(R, PAD);
  __syncthreads();

  // per-lane running bound: max over this lane's d (monotone decreasing)
  float mydone = 0.0f;
#pragma unroll
  for (int j = 0; j < T; ++j)
    mydone = fmaxf(mydone,
                   fmaxf(fmaxf(d[j][0], d[j][1]), fmaxf(d[j][2], d[j][3])));

  // exact lower envelope, +/- paired, wave-uniform dx^2.
  // Lane deactivates once kk^2 >= mydone (all remaining candidates dominated).
  bool alldone = false;
  for (int kk = 1; kk <= Rw; ++kk) {
    float fkk = (float)kk;
    float fk2 = fkk * fkk;
    bool act = (mydone > fk2);
    if (__all(!act)) { alldone = true; break; }
    if (act) {
#pragma unroll
      for (int j = 0; j < T; ++j) {
        float4 gm = *(const float4*)&g[j][x + PAD - kk][0];
        float4 gq = *(const float4*)&g[j][x + PAD + kk][0];
        d[j][0] = fminf(d[j][0], fminf(gm.x, gq.x) + fk2);
        d[j][1] = fminf(d[j][1], fminf(gm.y, gq.y) + fk2);
        d[j][2] = fminf(d[j][2], fminf(gm.z, gq.z) + fk2);
        d[j][3] = fminf(d[j][3], fminf(gm.w, gq.w) + fk2);
      }
      float md = 0.0f;
#pragma unroll
      for (int j = 0; j < T; ++j)
        md = fmaxf(md, fmaxf(fmaxf(d[j][0], d[j][1]), fmaxf(d[j][2], d[j][3])));
      mydone = md;
    }
  }
  if (!alldone && R > PAD) {           // exactness fallback; never hot
#pragma unroll 1
    for (int kk = PAD + 1; kk <= R; ++kk) {
      float fkk = (float)kk;
      float fk2 = fkk * fkk;
      bool act = (mydone > fk2);
      if (__all(!act)) break;
      if (act) {
        int xm = max(x - kk, 0), xp = min(x + kk, WW - 1);
        float dm = (float)(x - xm), dpq = (float)(xp - x);
        float dm2 = dm * dm, dp2 = dpq * dpq;
#pragma unroll
        for (int j = 0; j < T; ++j) {
          float4 gm = *(const float4*)&g[j][xm + PAD][0];
          float4 gq = *(const float4*)&g[j][xp + PAD][0];
          d[j][0] = fminf(d[j][0], fminf(gm.x + dm2, gq.x + dp2));
          d[j][1] = fminf(d[j][1], fminf(gm.y + dm2, gq.y + dp2));
          d[j][2] = fminf(d[j][2], fminf(gm.z + dm2, gq.z + dp2));
          d[j][3] = fminf(d[j][3], fminf(gm.w + dm2, gq.w + dp2));
        }
        float md = 0.0f;
#pragma unroll
        for (int j = 0; j < T; ++j)
          md = fmaxf(md, fmaxf(fmaxf(d[j][0], d[j][1]), fmaxf(d[j][2], d[j][3])));
        mydone = md;
      }
    }
  }

  // epilogue: softmax + boundary map; target class from the resident mask word
  float acc = 0.0f;
#pragma unroll
  for (int j = 0; j < T; ++j) {
    const int ly = (y0 + j) & 63;
    const int t = (int)((m[wy][1] >> ly) & 1ull) * 1 +
                  (int)((m[wy][2] >> ly) & 1ull) * 2 +
                  (int)((m[wy][3] >> ly) & 1ull) * 3;
    float p0 = pr[j][0], p1 = pr[j][1], p2 = pr[j][2], p3 = pr[j][3];
    float pm = fmaxf(fmaxf(p0, p1), fmaxf(p2, p3));
    float e0 = expf(p0 - pm), e1 = expf(p1 - pm);
    float e2 = expf(p2 - pm), e3 = expf(p3 - pm);
    float inv = 1.0f / (e0 + e1 + e2 + e3);

    float dn1 = fminf(d[j][0], fminf(d[j][2], d[j][3]));
    float dn2 = fminf(d[j][0], fminf(d[j][1], d[j][3]));
    float dn3 = fminf(d[j][0], fminf(d[j][1], d[j][2]));
    float c1 = (t == 1) ? (1.0f - sqrtf(dn1)) : sqrtf(d[j][1]);
    float c2 = (t == 2) ? (1.0f - sqrtf(dn2)) : sqrtf(d[j][2]);
    float c3 = (t == 3) ? (1.0f - sqrtf(dn3)) : sqrtf(d[j][3]);
    acc += (c1 * e1 + c2 * e2 + c3 * e3) * inv;
  }

  // block reduction -> single atomic
#pragma unroll
  for (int off = 32; off; off >>= 1) acc += __shfl_down(acc, off, 64);
  if ((x & 63) == 0) fred[x >> 6] = acc;
  __syncthreads();
  if (x == 0)
    atomicAdd(out, (fred[0] + fred[1] + fred[2] + fred[3]) *
                       (1.0f / (3.0f * BB * HH * WW)));
}

extern "C" void kernel_launch(void* const* d_in, const int* in_sizes, int n_in,
                              void* d_out, int out_size, void* d_ws, size_t ws_size,
                              hipStream_t stream) {
  const float* preds = (const float*)d_in[0];
  const int*   tgt   = (const int*)d_in[1];
  float* out   = (float*)d_out;
  u64*   masks = (u64*)d_ws;   // 8*4*256*4*8B = 256 KB

  void* args[] = {(void*)&tgt, (void*)&preds, (void*)&masks, (void*)&out};
  hipLaunchCooperativeKernel((const void*)mega, dim3(BB * (HH / T)), dim3(256),
                             args, 0, stream);
}

// Round 8
// 72.856 us; speedup vs baseline: 1.7436x; 1.7436x over previous
//
#include <hip/hip_runtime.h>
#include <math.h>

#define BB 8
#define HH 256
#define WW 256
#define T  4     // rows per fused block (must divide 64) — R4-verified optimum
#define NW 4     // 256 rows / 64 bits
#define PAD 96   // envelope window padding; R>PAD handled by exact fallback
#define LDSW (WW + 2 * PAD)

typedef unsigned long long u64;

// ---------------------------------------------------------------------------
// K0 (unchanged from R4, verified): per-column class presence bitmasks +
// zero the output accumulator. u64 layout (k innermost):
//   masks[((b*NW + w)*WW + x)*4 + k] bit ly <=> tgt[b][w*64+ly][x] == k.
// 256 blocks x 128 threads; each thread builds a 16-row u16 quarter-word.
// ---------------------------------------------------------------------------
__global__ __launch_bounds__(128) void build_masks(const int* __restrict__ tgt,
                                                   unsigned short* __restrict__ masks16,
                                                   float* __restrict__ out) {
  const int tx = threadIdx.x;           // 0..127
  const int xh = blockIdx.x & 1;        // x half
  const int b  = blockIdx.x >> 1;
  const int w  = blockIdx.y;            // u64 word = 64 rows
  const int q  = blockIdx.z;            // quarter: rows w*64+q*16 .. +15
  const int x  = xh * 128 + tx;
  if (b == 0 && w == 0 && q == 0 && x == 0) out[0] = 0.0f;
  unsigned m0 = 0, m1 = 0, m2 = 0, m3 = 0, bit = 1u;
  const int* p = tgt + ((size_t)b * HH + w * 64 + q * 16) * WW + x;
  for (int r = 0; r < 16; ++r, bit += bit) {
    int e = p[r * WW];                  // coalesced across x
    m0 |= (e == 0) ? bit : 0u;
    m1 |= (e == 1) ? bit : 0u;
    m2 |= (e == 2) ? bit : 0u;
    m3 |= (e == 3) ? bit : 0u;
  }
  unsigned short* mp = masks16 + (((size_t)(b * NW + w) * WW + x) * 4) * 4 + q;
  mp[0]  = (unsigned short)m0;          // k = 0
  mp[4]  = (unsigned short)m1;          // k = 1
  mp[8]  = (unsigned short)m2;          // k = 2
  mp[12] = (unsigned short)m3;          // k = 3
}

// ---------------------------------------------------------------------------
// K1 fused. R8: CLASS-SPLIT for 2x occupancy. 512-thread blocks; tid>>8
// selects a class pair (h=0 -> {0,1}, h=1 -> {2,3}). Each thread runs phase A
// + envelope for its 2 classes over all T rows (float2 LDS ops). Total work
// unchanged (2x waves x half work), TLP 2x (16 waves/CU), per-lane exit bound
// tighter (max over 2 classes). Epilogue: final d written back to g[x+PAD]
// slots + wy mask words exchanged via LDS; each half computes 2 of 4 rows.
// Same math as R4 (verified absmax 0.0) — only parallel decomposition changed.
// ---------------------------------------------------------------------------
__global__ __launch_bounds__(512, 4) void fused(const u64* __restrict__ masks,
                                                const float* __restrict__ preds,
                                                float* __restrict__ out) {
  __shared__ float g[T][LDSW][4];   // squared 1-D column distances, padded rows
  __shared__ u64 mws[WW][4];        // wy-word per class, for epilogue t-bits
  __shared__ float fred[8];
  const int tid = threadIdx.x;
  const int x  = tid & 255;
  const int h  = tid >> 8;          // class pair: {2h, 2h+1}
  const int b  = blockIdx.x;
  const int y0 = blockIdx.y * T;
  const int wy = y0 >> 6;           // T divides 64 -> same word for all tile rows

  // column masks for this x, this class pair: 4 words x 2 classes (16 B each)
  u64 m[NW][2];
  {
    const u64* mb = masks + ((size_t)b * NW * WW + x) * 4 + 2 * h;
#pragma unroll
    for (int w = 0; w < NW; ++w) {
      ulonglong2 v = *(const ulonglong2*)(mb + (size_t)w * WW * 4);
      m[w][0] = v.x; m[w][1] = v.y;
    }
  }
  // stash own wy-word pair for the epilogue's target-class bits
  mws[x][2 * h]     = m[wy][0];
  mws[x][2 * h + 1] = m[wy][1];

  // prefetch epilogue preds for this half's 2 rows (j = 2h, 2h+1)
  float pr[2][4];
#pragma unroll
  for (int jj = 0; jj < 2; ++jj) {
    const float* pb = preds + ((size_t)b * 4 * HH + (y0 + 2 * h + jj)) * WW + x;
    pr[jj][0] = pb[0 * HH * WW];
    pr[jj][1] = pb[1 * HH * WW];
    pr[jj][2] = pb[2 * HH * WW];
    pr[jj][3] = pb[3 * HH * WW];
  }

  // init padding to +INF (disjoint from the g[.][x+PAD] slots written below)
  for (int i = tid; i < T * 2 * PAD; i += 512) {
    int j = i / (2 * PAD);
    int q = i - j * (2 * PAD);
    int idx = (q < PAD) ? q : (q + WW);
    *(float4*)&g[j][idx][0] = make_float4(1e30f, 1e30f, 1e30f, 1e30f);
  }

  // phase A part 1: non-own words' nearest-bit positions (own 2 classes only)
  int posmax[2] = {-4096, -4096};
  int posmin[2] = { 8192,  8192};
#pragma unroll
  for (int w = 0; w < NW; ++w) {
    if (w < wy) {                    // wave-uniform branch (wy is scalar)
#pragma unroll
      for (int k = 0; k < 2; ++k) {
        u64 bits = m[w][k];
        int pos = w * 64 + 63 - __clzll((long long)bits);
        posmax[k] = max(posmax[k], bits ? pos : -4096);
      }
    } else if (w > wy) {
#pragma unroll
      for (int k = 0; k < 2; ++k) {
        u64 bits = m[w][k];
        int pos = w * 64 + (__ffsll((long long)bits) - 1);
        posmin[k] = min(posmin[k], bits ? pos : 8192);
      }
    }
  }

  // phase A part 2: per-row own-word eval + combine (all T rows, 2 classes)
  float d[T][2];                    // envelope seeds carried in registers
  int lmax = 0;
#pragma unroll
  for (int j = 0; j < T; ++j) {
    const int y  = y0 + j;
    const int ly = y & 63;
    const int ini = min(513 + y, 768 - y);   // reference INF-scan value
    float2 gv;
#pragma unroll
    for (int k = 0; k < 2; ++k) {
      u64 bits = m[wy][k];
      u64 lo = bits & ((2ull << ly) - 1ull);  // bits 0..ly (ly=63 -> ~0)
      u64 hi = bits >> ly;                    // bit0 == bit ly
      int dl = ly - 63 + __clzll((long long)lo);
      int dh = __ffsll((long long)hi) - 1;
      int best = min(ini, y - posmax[k]);
      best = min(best, posmin[k] - y);
      best = min(best, lo ? dl : 1024);
      best = min(best, hi ? dh : 1024);
      lmax = max(lmax, best);
      float fb = (float)(best * best);
      ((float*)&gv)[k] = fb;
      d[j][k] = fb;                // kk = 0 seed, no LDS round-trip
    }
    *(float2*)&g[j][x + PAD][2 * h] = gv;
  }

  // per-wave static radius bound (wave = 64 lanes, single h, 2 classes).
  // Each lane's own-column 1-D distance bounds its useful radius; wave-max
  // over its lanes/rows/classes bounds every lane this wave updates. Exact.
#pragma unroll
  for (int off = 32; off; off >>= 1) lmax = max(lmax, __shfl_xor(lmax, off, 64));
  const int R  = __builtin_amdgcn_readfirstlane(lmax);
  const int Rw = min(R, PAD);
  __syncthreads();

  // per-lane running bound: max over this lane's d (monotone decreasing)
  float mydone = 0.0f;
#pragma unroll
  for (int j = 0; j < T; ++j)
    mydone = fmaxf(mydone, fmaxf(d[j][0], d[j][1]));

  // exact lower envelope, +/- paired, wave-uniform dx^2, float2 per row.
  // Lane deactivates once kk^2 >= mydone (all remaining candidates dominated:
  // g >= 0 so candidate >= kk^2 >= current d). Wave breaks when all inactive.
  bool alldone = false;
  for (int kk = 1; kk <= Rw; ++kk) {
    float fkk = (float)kk;
    float fk2 = fkk * fkk;
    bool act = (mydone > fk2);
    if (__all(!act)) { alldone = true; break; }
    if (act) {
#pragma unroll
      for (int j = 0; j < T; ++j) {
        float2 gm = *(const float2*)&g[j][x + PAD - kk][2 * h];
        float2 gq = *(const float2*)&g[j][x + PAD + kk][2 * h];
        d[j][0] = fminf(d[j][0], fminf(gm.x, gq.x) + fk2);
        d[j][1] = fminf(d[j][1], fminf(gm.y, gq.y) + fk2);
      }
      float md = 0.0f;
#pragma unroll
      for (int j = 0; j < T; ++j)
        md = fmaxf(md, fmaxf(d[j][0], d[j][1]));
      mydone = md;
    }
  }
  if (!alldone && R > PAD) {           // exactness fallback; never hot
#pragma unroll 1
    for (int kk = PAD + 1; kk <= R; ++kk) {
      float fkk = (float)kk;
      float fk2 = fkk * fkk;
      bool act = (mydone > fk2);
      if (__all(!act)) break;
      if (act) {
        int xm = max(x - kk, 0), xp = min(x + kk, WW - 1);
        float dm = (float)(x - xm), dpq = (float)(xp - x);
        float dm2 = dm * dm, dp2 = dpq * dpq;
#pragma unroll
        for (int j = 0; j < T; ++j) {
          float2 gm = *(const float2*)&g[j][xm + PAD][2 * h];
          float2 gq = *(const float2*)&g[j][xp + PAD][2 * h];
          d[j][0] = fminf(d[j][0], fminf(gm.x + dm2, gq.x + dp2));
          d[j][1] = fminf(d[j][1], fminf(gm.y + dm2, gq.y + dp2));
        }
        float md = 0.0f;
#pragma unroll
        for (int j = 0; j < T; ++j)
          md = fmaxf(md, fmaxf(d[j][0], d[j][1]));
        mydone = md;
      }
    }
  }

  // exchange final d via the (now-consumed) g[x+PAD] slots
  __syncthreads();                     // all envelope reads of g complete
#pragma unroll
  for (int j = 0; j < T; ++j)
    *(float2*)&g[j][x + PAD][2 * h] = make_float2(d[j][0], d[j][1]);
  __syncthreads();

  // epilogue: softmax + boundary map; each half computes rows j = 2h, 2h+1
  float acc = 0.0f;
#pragma unroll
  for (int jj = 0; jj < 2; ++jj) {
    const int j  = 2 * h + jj;
    const int ly = (y0 + j) & 63;
    const int t = (int)((mws[x][1] >> ly) & 1ull) * 1 +
                  (int)((mws[x][2] >> ly) & 1ull) * 2 +
                  (int)((mws[x][3] >> ly) & 1ull) * 3;
    float4 dj = *(const float4*)&g[j][x + PAD][0];
    float p0 = pr[jj][0], p1 = pr[jj][1], p2 = pr[jj][2], p3 = pr[jj][3];
    float pm = fmaxf(fmaxf(p0, p1), fmaxf(p2, p3));
    float e0 = expf(p0 - pm), e1 = expf(p1 - pm);
    float e2 = expf(p2 - pm), e3 = expf(p3 - pm);
    float inv = 1.0f / (e0 + e1 + e2 + e3);

    float dn1 = fminf(dj.x, fminf(dj.z, dj.w));
    float dn2 = fminf(dj.x, fminf(dj.y, dj.w));
    float dn3 = fminf(dj.x, fminf(dj.y, dj.z));
    float c1 = (t == 1) ? (1.0f - sqrtf(dn1)) : sqrtf(dj.y);
    float c2 = (t == 2) ? (1.0f - sqrtf(dn2)) : sqrtf(dj.z);
    float c3 = (t == 3) ? (1.0f - sqrtf(dn3)) : sqrtf(dj.w);
    acc += (c1 * e1 + c2 * e2 + c3 * e3) * inv;
  }

  // block reduction (8 waves) -> single atomic
#pragma unroll
  for (int off = 32; off; off >>= 1) acc += __shfl_down(acc, off, 64);
  if ((tid & 63) == 0) fred[tid >> 6] = acc;
  __syncthreads();
  if (tid == 0) {
    float s = fred[0] + fred[1] + fred[2] + fred[3] +
              fred[4] + fred[5] + fred[6] + fred[7];
    atomicAdd(out, s * (1.0f / (3.0f * BB * HH * WW)));
  }
}

extern "C" void kernel_launch(void* const* d_in, const int* in_sizes, int n_in,
                              void* d_out, int out_size, void* d_ws, size_t ws_size,
                              hipStream_t stream) {
  const float* preds = (const float*)d_in[0];
  const int*   tgt   = (const int*)d_in[1];
  float* out   = (float*)d_out;
  u64*   masks = (u64*)d_ws;   // 8*4*256*4*8B = 256 KB

  build_masks<<<dim3(BB * 2, NW, 4), 128, 0, stream>>>(tgt, (unsigned short*)masks, out);
  fused<<<dim3(BB, HH / T), 512, 0, stream>>>(masks, preds, out);
}